// Round 15
// baseline (526.500 us; speedup 1.0000x reference)
//
#include <hip/hip_runtime.h>

#define SEQ 640
#define BATCH 40
#define D_IN 8
#define D_TRAJ 32
#define D_LSTM 64
#define G4 256        // 4 * D_LSTM
#define NH 4
#define DH 48
#define EMB 192
#define NLSTM 40      // producer blocks (one per batch)
#define NPERS 472     // persistent attn consumer blocks (total 512: all resident)

typedef float v2f __attribute__((ext_vector_type(2)));
typedef float v4f __attribute__((ext_vector_type(4)));
typedef _Float16 h2t __attribute__((ext_vector_type(2)));

__device__ __forceinline__ float sigmoid_f(float x) {
    float e = __expf(-x);
    return __builtin_amdgcn_rcpf(1.f + e);
}
__device__ __forceinline__ float tanh_f(float x) {
    float e = __expf(2.f * x);
    return 1.f - 2.f * __builtin_amdgcn_rcpf(e + 1.f);
}

// ---------------------------------------------------------------------------
// Kernel 1: trajectory embed (ELU) + gate precompute — R8-EXACT math.
// Also zeroes prog[0..39] (block 0) for the mega kernel's progress sync.
// grid: 640 blocks (t), 256 threads.
// ---------------------------------------------------------------------------
__global__ void __launch_bounds__(256) k_embed(
    const float* __restrict__ hist, const float* __restrict__ W1,
    const float* __restrict__ b1, const float* __restrict__ W_ih,
    const float* __restrict__ b_ih, const float* __restrict__ b_hh,
    float* __restrict__ gates_x, int* __restrict__ prog)
{
    __shared__ float sh_hist[BATCH * D_IN];                   // 320
    __shared__ __align__(16) float sh_traj[BATCH * D_TRAJ];   // 1280
    const int t = blockIdx.x, tid = threadIdx.x;

    if (blockIdx.x == 0 && tid < NLSTM)
        __hip_atomic_store(&prog[tid], 0, __ATOMIC_RELAXED,
                           __HIP_MEMORY_SCOPE_AGENT);

    for (int i = tid; i < BATCH * D_IN; i += 256)
        sh_hist[i] = hist[t * BATCH * D_IN + i];
    __syncthreads();

    for (int idx = tid; idx < BATCH * D_TRAJ; idx += 256) {
        int b = idx >> 5, h = idx & 31;
        float acc = b1[h];
        #pragma unroll
        for (int f = 0; f < D_IN; ++f)
            acc += sh_hist[b * D_IN + f] * W1[h * D_IN + f];
        sh_traj[idx] = acc > 0.f ? acc : (__expf(acc) - 1.f);   // ELU
    }
    __syncthreads();

    float w[D_TRAJ];
    {
        const v4f* wv = (const v4f*)(W_ih + tid * D_TRAJ);
        #pragma unroll
        for (int u = 0; u < 8; ++u) {
            v4f x = wv[u];
            w[4*u] = x.x; w[4*u+1] = x.y; w[4*u+2] = x.z; w[4*u+3] = x.w;
        }
    }
    const float bias = b_ih[tid] + b_hh[tid];
    const int j = tid & 63, g = tid >> 6;       // unit, gate-type

    for (int b = 0; b < BATCH; ++b) {
        const v4f* tp = (const v4f*)&sh_traj[b * D_TRAJ];  // 128B-aligned rows
        float acc = bias;
        #pragma unroll
        for (int u = 0; u < 8; ++u) {
            v4f tv = tp[u];
            acc += tv.x * w[4*u];
            acc += tv.y * w[4*u+1];
            acc += tv.z * w[4*u+2];
            acc += tv.w * w[4*u+3];
        }
        // [b][g][t][j] — coalesced per-wave per-step read in k_lstm
        gates_x[(((size_t)b * 4 + g) * SEQ + t) * 64 + j] = acc;
    }
}

// ---------------------------------------------------------------------------
// Kernel 2 (MEGA): LSTM producers (0..39) + persistent attn consumers
// (40..511), one launch, prog[b] progress sync.
// R14 post-mortem: producer 230->375us from (1) CU-sharing with busy
// consumer waves (latency chain vs issue competition) and (2) every-step
// __syncthreads draining vmcnt(0) on the slow agent-scope seq store
// (MALL ack ~500-700cy). R15 fixes: (1) s_setprio(3) on producer waves
// (consumers default 0 -> fill only producer stall slots); (2) R3-proven
// lgkm-only barrier per step; vmcnt(0) drain only at publish points
// (every 8 steps, wave 0 only — the only wave storing seq) + at end.
// All arithmetic unchanged (R1 lstm / R11 attn verbatim).
// grid: 512 blocks x 256 threads.
// ---------------------------------------------------------------------------
#define SAS 68     // f32 stride of sA rows (16B-aligned)
#define SKVS 152   // f16 stride of qkv rows (304B, 16B-aligned): q@0,k@48,v@96
#define SSS 44     // f32 stride for score rows
__global__ void __launch_bounds__(256) k_mega(
    const float* __restrict__ gates_x, const float* __restrict__ W_hh,
    float* __restrict__ seq_out,
    const float* __restrict__ Wq, const float* __restrict__ bq,
    const float* __restrict__ Wk, const float* __restrict__ bk,
    const float* __restrict__ Wv, const float* __restrict__ bv,
    float* __restrict__ o_buf, int* __restrict__ prog)
{
    __shared__ float sg[2][4][64];                     // lstm gate exchange
    __shared__ __align__(16) float sA[BATCH * SAS];    // attn: seq_t stage
    __shared__ _Float16 skqv[BATCH * SKVS];            // attn: q,k,v (f16)
    __shared__ float ss[BATCH * SSS];                  // attn: scores

    const int tid = threadIdx.x;

    if (blockIdx.x < NLSTM) {
        // ================= LSTM producer (R1-exact math) =================
        __builtin_amdgcn_s_setprio(3);   // favor the recurrence chain
        const int b = blockIdx.x;
        const int g = tid >> 6;      // wave id == gate (i, f, g, o)
        const int j = tid & 63;      // unit

        h2t w2[32];
        {
            const float* Wrow = W_hh + (g * 64 + j) * D_LSTM;
            #pragma unroll
            for (int m = 0; m < 32; ++m)
                w2[m] = (h2t){(_Float16)Wrow[2*m], (_Float16)Wrow[2*m+1]};
        }

        const float* gx = gates_x + (((size_t)b * 4 + g) * SEQ) * 64 + j;
        float gq0 = gx[0 * 64];
        float gq1 = gx[1 * 64];
        float gq2 = gx[2 * 64];
        float gq3 = gx[3 * 64];

        float h = 0.f, c = 0.f;
        float hpf = 0.f;
        const bool odd = (j & 1);

        auto step = [&](float& gq, int t) {
            const int hbits = __builtin_bit_cast(int, hpf);

            float a0 = gq, a1 = 0.f, a2 = 0.f, a3 = 0.f;
            #pragma unroll
            for (int m = 0; m < 8; ++m) {
                h2t p = __builtin_bit_cast(h2t, __builtin_amdgcn_readlane(hbits, 2*m));
                a0 = __builtin_amdgcn_fdot2(w2[m], p, a0, false);
            }
            #pragma unroll
            for (int m = 8; m < 16; ++m) {
                h2t p = __builtin_bit_cast(h2t, __builtin_amdgcn_readlane(hbits, 2*m));
                a1 = __builtin_amdgcn_fdot2(w2[m], p, a1, false);
            }
            #pragma unroll
            for (int m = 16; m < 24; ++m) {
                h2t p = __builtin_bit_cast(h2t, __builtin_amdgcn_readlane(hbits, 2*m));
                a2 = __builtin_amdgcn_fdot2(w2[m], p, a2, false);
            }
            #pragma unroll
            for (int m = 24; m < 32; ++m) {
                h2t p = __builtin_bit_cast(h2t, __builtin_amdgcn_readlane(hbits, 2*m));
                a3 = __builtin_amdgcn_fdot2(w2[m], p, a3, false);
            }
            float a = (a0 + a1) + (a2 + a3);

            // R3-proven lgkm-only barrier: agent store + prefetch stay
            // in flight across the barrier.
            const int buf = t & 1;
            sg[buf][g][j] = a;
            asm volatile("s_waitcnt lgkmcnt(0)" ::: "memory");
            __builtin_amdgcn_s_barrier();
            asm volatile("" ::: "memory");

            // publish every 8 steps: wave 0 (the seq-storing wave) drains
            // its outstanding stores, then publishes prog[b]=t
            // (= steps 0..t-1 complete & visible).
            if ((t & 7) == 0 && tid == 0) {
                asm volatile("s_waitcnt vmcnt(0)" ::: "memory");
                __hip_atomic_store(&prog[b], t, __ATOMIC_RELAXED,
                                   __HIP_MEMORY_SCOPE_AGENT);
            }

            float ai = sg[buf][0][j];
            float af = sg[buf][1][j];
            float ag = sg[buf][2][j];
            float ao = sg[buf][3][j];

            c = sigmoid_f(af) * c + sigmoid_f(ai) * tanh_f(ag);
            h = sigmoid_f(ao) * tanh_f(c);
            if (g == 0)
                __hip_atomic_store(&seq_out[(size_t)(t * BATCH + b) * D_LSTM + j],
                                   h, __ATOMIC_RELAXED, __HIP_MEMORY_SCOPE_AGENT);

            int own = (int)__builtin_bit_cast(unsigned short, (_Float16)h);
            int nb  = __builtin_amdgcn_update_dpp(0, own, 0xB1, 0xF, 0xF, true);
            int pk  = odd ? (nb | (own << 16)) : (own | (nb << 16));
            hpf = __builtin_bit_cast(float, pk);

            int tp = t + 4; if (tp > SEQ - 1) tp = SEQ - 1;
            gq = gx[(size_t)tp * 64];
        };

        for (int t = 0; t < SEQ; t += 4) {
            step(gq0, t + 0);
            step(gq1, t + 1);
            step(gq2, t + 2);
            step(gq3, t + 3);
        }
        // final publish: all 640 steps stored and drained
        asm volatile("s_waitcnt vmcnt(0)" ::: "memory");
        if (tid == 0)
            __hip_atomic_store(&prog[b], SEQ, __ATOMIC_RELAXED,
                               __HIP_MEMORY_SCOPE_AGENT);
        return;
    }

    // ================= persistent attn consumers (R11-verbatim math) ======
    const int p = blockIdx.x - NLSTM;
    for (int item = p; item < NH * SEQ; item += NPERS) {
        const int t  = item >> 2;     // increasing t per block
        const int hd = item & 3;

        // ---- wait until all 40 producers have passed step t ----
        if (tid < 64) {
            while (true) {
                int v = (tid < NLSTM)
                    ? __hip_atomic_load(&prog[tid], __ATOMIC_RELAXED,
                                        __HIP_MEMORY_SCOPE_AGENT)
                    : SEQ;
                if (!__any(v <= t)) break;   // need v >= t+1 for all b
                __builtin_amdgcn_s_sleep(8);
            }
        }
        __syncthreads();

        // ---- stage seq_t (agent-coherent loads) ----
        for (int i = tid; i < BATCH * D_LSTM; i += 256)
            sA[(i >> 6) * SAS + (i & 63)] =
                __hip_atomic_load(&seq_out[(size_t)t * BATCH * D_LSTM + i],
                                  __ATOMIC_RELAXED, __HIP_MEMORY_SCOPE_AGENT);
        __syncthreads();

        // ---- projection (R11-verbatim) ----
        if (tid < 144) {
            int m = tid / 48, d = tid - m * 48;
            const float* W = (m == 0) ? Wq : (m == 1) ? Wk : Wv;
            const float* B = (m == 0) ? bq : (m == 1) ? bk : bv;
            const float* wrow = W + (hd * DH + d) * D_LSTM;
            float wreg[D_LSTM];
            {
                const v4f* wv = (const v4f*)wrow;
                #pragma unroll
                for (int u = 0; u < 16; ++u) {
                    v4f x = wv[u];
                    wreg[4*u] = x.x; wreg[4*u+1] = x.y;
                    wreg[4*u+2] = x.z; wreg[4*u+3] = x.w;
                }
            }
            const float bias = B[hd * DH + d];

            for (int a = 0; a < BATCH; ++a) {
                const v4f* ap = (const v4f*)&sA[a * SAS];
                float acc = bias;
                v4f av[8];
                #pragma unroll
                for (int u = 0; u < 8; ++u) av[u] = ap[u];
                #pragma unroll
                for (int u = 0; u < 8; ++u) {
                    acc += av[u].x * wreg[4*u]   + av[u].y * wreg[4*u+1]
                         + av[u].z * wreg[4*u+2] + av[u].w * wreg[4*u+3];
                }
                #pragma unroll
                for (int u = 0; u < 8; ++u) av[u] = ap[8 + u];
                #pragma unroll
                for (int u = 0; u < 8; ++u) {
                    acc += av[u].x * wreg[32+4*u]   + av[u].y * wreg[32+4*u+1]
                         + av[u].z * wreg[32+4*u+2] + av[u].w * wreg[32+4*u+3];
                }
                skqv[a * SKVS + tid] = (_Float16)acc;
            }
        }
        __syncthreads();

        // ---- scores = q k^T / 8 (R11-verbatim) ----
        for (int idx = tid; idx < BATCH * BATCH; idx += 256) {
            int i = idx / BATCH, jj = idx % BATCH;
            const v4f* qp = (const v4f*)&skqv[i * SKVS];
            const v4f* kp = (const v4f*)&skqv[jj * SKVS + 48];
            float acc = 0.f;
            #pragma unroll
            for (int u = 0; u < 6; ++u) {
                v4f qv = qp[u], kv = kp[u];
                acc = __builtin_amdgcn_fdot2(__builtin_bit_cast(h2t, qv.x),
                        __builtin_bit_cast(h2t, kv.x), acc, false);
                acc = __builtin_amdgcn_fdot2(__builtin_bit_cast(h2t, qv.y),
                        __builtin_bit_cast(h2t, kv.y), acc, false);
                acc = __builtin_amdgcn_fdot2(__builtin_bit_cast(h2t, qv.z),
                        __builtin_bit_cast(h2t, kv.z), acc, false);
                acc = __builtin_amdgcn_fdot2(__builtin_bit_cast(h2t, qv.w),
                        __builtin_bit_cast(h2t, kv.w), acc, false);
            }
            ss[i * SSS + jj] = acc * 0.125f;
        }
        __syncthreads();

        // ---- row softmax: 4-lane groups (R11-verbatim) ----
        if (tid < 160) {
            const int gr = tid >> 2, ll = tid & 3;
            float* row = &ss[gr * SSS];
            float v[10];
            float lm = -1e30f;
            #pragma unroll
            for (int k = 0; k < 10; ++k) {
                v[k] = row[ll + 4 * k];
                lm = fmaxf(lm, v[k]);
            }
            lm = fmaxf(lm, __shfl_xor(lm, 1, 64));
            lm = fmaxf(lm, __shfl_xor(lm, 2, 64));
            float s = 0.f;
            #pragma unroll
            for (int k = 0; k < 10; ++k) { v[k] = __expf(v[k] - lm); s += v[k]; }
            s += __shfl_xor(s, 1, 64);
            s += __shfl_xor(s, 2, 64);
            float inv = __builtin_amdgcn_rcpf(s);
            #pragma unroll
            for (int k = 0; k < 10; ++k) row[ll + 4 * k] = v[k] * inv;
        }
        __syncthreads();

        // ---- AV (R11-verbatim) ----
        if (tid < 240) {
            int bi = tid / 6, dg = tid % 6, d0 = dg * 8;
            const v4f* sp = (const v4f*)&ss[bi * SSS];
            v4f sr[10];
            #pragma unroll
            for (int u = 0; u < 10; ++u) sr[u] = sp[u];
            float acc[8];
            #pragma unroll
            for (int d = 0; d < 8; ++d) acc[d] = 0.f;
            for (int jj = 0; jj < 40; jj += 4) {
                v4f vv[4];
                #pragma unroll
                for (int q = 0; q < 4; ++q)
                    vv[q] = *(const v4f*)&skqv[(jj + q) * SKVS + 96 + d0];
                #pragma unroll
                for (int q = 0; q < 4; ++q) {
                    float a = ((const float*)&sr[(jj + q) >> 2])[(jj + q) & 3];
                    #pragma unroll
                    for (int w = 0; w < 4; ++w) {
                        h2t pr = __builtin_bit_cast(h2t, ((const float*)&vv[q])[w]);
                        acc[2 * w]     += a * (float)pr[0];
                        acc[2 * w + 1] += a * (float)pr[1];
                    }
                }
            }
            float* ob = &o_buf[((size_t)t * BATCH + bi) * EMB + hd * DH + d0];
            *(v4f*)&ob[0] = (v4f){acc[0], acc[1], acc[2], acc[3]};
            *(v4f*)&ob[4] = (v4f){acc[4], acc[5], acc[6], acc[7]};
        }
        __syncthreads();   // skqv/ss/sA reused by next item
    }
}

// ---------------------------------------------------------------------------
// Kernel 3: GLU + residual + LayerNorm — R8-proven verbatim.
// grid: 640 blocks, 256 threads.
// ---------------------------------------------------------------------------
__global__ void __launch_bounds__(256) k_glu_ln(
    const float* __restrict__ seq, const float* __restrict__ obuf,
    const float* __restrict__ Wa, const float* __restrict__ ba,
    const float* __restrict__ Wg, const float* __restrict__ bg,
    const float* __restrict__ gamma, const float* __restrict__ beta,
    float* __restrict__ out)
{
    const int t = blockIdx.x, tid = threadIdx.x;
    __shared__ __align__(16) float so[BATCH * 196];   // o_t padded (16B rows)
    __shared__ float sy[BATCH * 65];                  // y padded
    __shared__ float sseq[BATCH * D_LSTM];

    const float* ot = obuf + (size_t)t * BATCH * EMB;
    for (int i = tid; i < BATCH * EMB; i += 256)
        so[(i / EMB) * 196 + (i % EMB)] = ot[i];
    for (int i = tid; i < BATCH * D_LSTM; i += 256)
        sseq[i] = seq[(size_t)t * BATCH * D_LSTM + i];
    __syncthreads();

    const int j = tid >> 2, bgr = tid & 3;
    float acc_a[10], acc_g[10];
    #pragma unroll
    for (int bb = 0; bb < 10; ++bb) { acc_a[bb] = ba[j]; acc_g[bb] = bg[j]; }

    const v4f* wav = (const v4f*)(Wa + j * EMB);   // 768B rows, 16B-aligned
    const v4f* wgv = (const v4f*)(Wg + j * EMB);
    for (int p4 = 0; p4 < EMB / 4; ++p4) {
        v4f av = wav[p4], gv = wgv[p4];
        #pragma unroll
        for (int bb = 0; bb < 10; ++bb) {
            v4f ov = *(const v4f*)&so[(bgr + 4 * bb) * 196 + 4 * p4];
            acc_a[bb] += ov.x * av.x;
            acc_a[bb] += ov.y * av.y;
            acc_a[bb] += ov.z * av.z;
            acc_a[bb] += ov.w * av.w;
            acc_g[bb] += ov.x * gv.x;
            acc_g[bb] += ov.y * gv.y;
            acc_g[bb] += ov.z * gv.z;
            acc_g[bb] += ov.w * gv.w;
        }
    }
    #pragma unroll
    for (int bb = 0; bb < 10; ++bb) {
        int b = bgr + 4 * bb;
        float tv = acc_a[bb] * sigmoid_f(acc_g[bb]);
        sy[b * 65 + j] = sseq[b * D_LSTM + j] + tv;
    }
    __syncthreads();

    const int w = tid >> 6, lane = tid & 63;
    const float gm = gamma[lane], bt = beta[lane];
    for (int rr = 0; rr < 10; ++rr) {
        int b = w + 4 * rr;
        float y = sy[b * 65 + lane];
        float s1 = y, s2 = y * y;
        #pragma unroll
        for (int m = 1; m < 64; m <<= 1) {
            s1 += __shfl_xor(s1, m, 64);
            s2 += __shfl_xor(s2, m, 64);
        }
        float mu  = s1 * (1.f / 64.f);
        float var = s2 * (1.f / 64.f) - mu * mu;
        float inv = rsqrtf(var + 1e-5f);
        out[(size_t)t * BATCH * D_LSTM + b * D_LSTM + lane] =
            (y - mu) * inv * gm + bt;
    }
}

// ---------------------------------------------------------------------------
extern "C" void kernel_launch(void* const* d_in, const int* in_sizes, int n_in,
                              void* d_out, int out_size, void* d_ws, size_t ws_size,
                              hipStream_t stream)
{
    const float* hist = (const float*)d_in[0];
    // d_in[1] adj: unused (use_spatial=False)
    const float* W1   = (const float*)d_in[2];
    const float* b1   = (const float*)d_in[3];
    const float* W_ih = (const float*)d_in[4];
    const float* W_hh = (const float*)d_in[5];
    const float* b_ih = (const float*)d_in[6];
    const float* b_hh = (const float*)d_in[7];
    const float* Wq   = (const float*)d_in[8];
    const float* bq   = (const float*)d_in[9];
    const float* Wk   = (const float*)d_in[10];
    const float* bk   = (const float*)d_in[11];
    const float* Wv   = (const float*)d_in[12];
    const float* bv   = (const float*)d_in[13];
    const float* Wa   = (const float*)d_in[14];
    const float* ba   = (const float*)d_in[15];
    const float* Wg   = (const float*)d_in[16];
    const float* bg   = (const float*)d_in[17];
    const float* gamma = (const float*)d_in[18];
    const float* beta  = (const float*)d_in[19];
    float* out = (float*)d_out;

    float* ws = (float*)d_ws;
    float* gates_x = ws;                                   // 640*40*256 f
    float* seq     = ws + 6553600;                         // 640*40*64 f
    float* obuf    = ws + 6553600 + 1638400;               // 640*40*192 f
    // progress array lives in d_out (harness memsets it; k_embed re-zeroes;
    // k_glu_ln fully overwrites out afterwards)
    int* prog = (int*)d_out;

    hipLaunchKernelGGL(k_embed, dim3(SEQ), dim3(256), 0, stream,
                       hist, W1, b1, W_ih, b_ih, b_hh, gates_x, prog);
    hipLaunchKernelGGL(k_mega, dim3(NLSTM + NPERS), dim3(256), 0, stream,
                       gates_x, W_hh, seq, Wq, bq, Wk, bk, Wv, bv, obuf, prog);
    hipLaunchKernelGGL(k_glu_ln, dim3(SEQ), dim3(256), 0, stream,
                       seq, obuf, Wa, ba, Wg, bg, gamma, beta, out);
}

// Round 17
// 458.190 us; speedup vs baseline: 1.1491x; 1.1491x over previous
//
#include <hip/hip_runtime.h>

#define SEQ 640
#define BATCH 40
#define D_IN 8
#define D_TRAJ 32
#define D_LSTM 64
#define G4 256        // 4 * D_LSTM
#define NH 4
#define DH 48
#define EMB 192

typedef float v2f __attribute__((ext_vector_type(2)));
typedef float v4f __attribute__((ext_vector_type(4)));
typedef _Float16 h2t __attribute__((ext_vector_type(2)));

__device__ __forceinline__ float sigmoid_f(float x) {
    float e = __expf(-x);
    return __builtin_amdgcn_rcpf(1.f + e);
}
__device__ __forceinline__ float tanh_f(float x) {
    float e = __expf(2.f * x);
    return 1.f - 2.f * __builtin_amdgcn_rcpf(e + 1.f);
}

// ---------------------------------------------------------------------------
// Kernel 1: trajectory embed (ELU) + gate precompute — R8-EXACT.
// gates_x layout [b][g][t][j]; v4f sh_traj reads.
// grid: 640 blocks (t), 256 threads.
// ---------------------------------------------------------------------------
__global__ void __launch_bounds__(256) k_embed(
    const float* __restrict__ hist, const float* __restrict__ W1,
    const float* __restrict__ b1, const float* __restrict__ W_ih,
    const float* __restrict__ b_ih, const float* __restrict__ b_hh,
    float* __restrict__ gates_x)
{
    __shared__ float sh_hist[BATCH * D_IN];                   // 320
    __shared__ __align__(16) float sh_traj[BATCH * D_TRAJ];   // 1280
    const int t = blockIdx.x, tid = threadIdx.x;

    for (int i = tid; i < BATCH * D_IN; i += 256)
        sh_hist[i] = hist[t * BATCH * D_IN + i];
    __syncthreads();

    for (int idx = tid; idx < BATCH * D_TRAJ; idx += 256) {
        int b = idx >> 5, h = idx & 31;
        float acc = b1[h];
        #pragma unroll
        for (int f = 0; f < D_IN; ++f)
            acc += sh_hist[b * D_IN + f] * W1[h * D_IN + f];
        sh_traj[idx] = acc > 0.f ? acc : (__expf(acc) - 1.f);   // ELU
    }
    __syncthreads();

    float w[D_TRAJ];
    {
        const v4f* wv = (const v4f*)(W_ih + tid * D_TRAJ);
        #pragma unroll
        for (int u = 0; u < 8; ++u) {
            v4f x = wv[u];
            w[4*u] = x.x; w[4*u+1] = x.y; w[4*u+2] = x.z; w[4*u+3] = x.w;
        }
    }
    const float bias = b_ih[tid] + b_hh[tid];
    const int j = tid & 63, g = tid >> 6;       // unit, gate-type

    for (int b = 0; b < BATCH; ++b) {
        const v4f* tp = (const v4f*)&sh_traj[b * D_TRAJ];  // 128B-aligned rows
        float acc = bias;
        #pragma unroll
        for (int u = 0; u < 8; ++u) {
            v4f tv = tp[u];
            acc += tv.x * w[4*u];
            acc += tv.y * w[4*u+1];
            acc += tv.z * w[4*u+2];
            acc += tv.w * w[4*u+3];
        }
        // [b][g][t][j] — coalesced per-wave per-step read in k_lstm
        gates_x[(((size_t)b * 4 + g) * SEQ + t) * 64 + j] = acc;
    }
}

// ---------------------------------------------------------------------------
// Kernel 2: LSTM recurrence — R1/R8-EXACT (229.8 us, absmax 0.015625). FROZEN.
// (6 alternative structures tried R2-R10; all equal or worse. R14/R15
// producer-consumer overlap: net-negative from CU-sharing interference.)
// grid: 40 blocks x 256 threads.
// ---------------------------------------------------------------------------
__global__ void __launch_bounds__(256, 1) k_lstm(
    const float* __restrict__ gates_x, const float* __restrict__ W_hh,
    float* __restrict__ seq_out)
{
    const int b = blockIdx.x;
    const int tid = threadIdx.x;
    const int g = tid >> 6;      // wave id == gate (i, f, g, o)
    const int j = tid & 63;      // unit

    __shared__ float sg[2][4][64];   // double-buffered raw gate sums

    // f16-packed recurrent weight row for (gate g, unit j)
    h2t w2[32];
    {
        const float* Wrow = W_hh + (g * 64 + j) * D_LSTM;
        #pragma unroll
        for (int m = 0; m < 32; ++m)
            w2[m] = (h2t){(_Float16)Wrow[2*m], (_Float16)Wrow[2*m+1]};
    }

    // x-side gate stream: [b][g][t][j], one dword per lane per step
    const float* gx = gates_x + (((size_t)b * 4 + g) * SEQ) * 64 + j;
    float gq0 = gx[0 * 64];
    float gq1 = gx[1 * 64];
    float gq2 = gx[2 * 64];
    float gq3 = gx[3 * 64];

    float h = 0.f, c = 0.f;
    float hpf = 0.f;                 // packed f16 pair (h_{2m}, h_{2m+1})
    const bool odd = (j & 1);

    auto step = [&](float& gq, int t) {
        const int hbits = __builtin_bit_cast(int, hpf);

        // gate-g matvec: 4 independent chains of 8 fdot2
        float a0 = gq, a1 = 0.f, a2 = 0.f, a3 = 0.f;
        #pragma unroll
        for (int m = 0; m < 8; ++m) {
            h2t p = __builtin_bit_cast(h2t, __builtin_amdgcn_readlane(hbits, 2*m));
            a0 = __builtin_amdgcn_fdot2(w2[m], p, a0, false);
        }
        #pragma unroll
        for (int m = 8; m < 16; ++m) {
            h2t p = __builtin_bit_cast(h2t, __builtin_amdgcn_readlane(hbits, 2*m));
            a1 = __builtin_amdgcn_fdot2(w2[m], p, a1, false);
        }
        #pragma unroll
        for (int m = 16; m < 24; ++m) {
            h2t p = __builtin_bit_cast(h2t, __builtin_amdgcn_readlane(hbits, 2*m));
            a2 = __builtin_amdgcn_fdot2(w2[m], p, a2, false);
        }
        #pragma unroll
        for (int m = 24; m < 32; ++m) {
            h2t p = __builtin_bit_cast(h2t, __builtin_amdgcn_readlane(hbits, 2*m));
            a3 = __builtin_amdgcn_fdot2(w2[m], p, a3, false);
        }
        float a = (a0 + a1) + (a2 + a3);

        // exchange gates (conflict-free: wave g writes contiguous row g)
        const int buf = t & 1;
        sg[buf][g][j] = a;
        __syncthreads();
        float ai = sg[buf][0][j];
        float af = sg[buf][1][j];
        float ag = sg[buf][2][j];
        float ao = sg[buf][3][j];

        // redundant identical (c,h) update in every wave
        c = sigmoid_f(af) * c + sigmoid_f(ai) * tanh_f(ag);
        h = sigmoid_f(ao) * tanh_f(c);
        if (g == 0)
            seq_out[(size_t)(t * BATCH + b) * D_LSTM + j] = h;

        // pack (h_2m, h_2m+1) as f16 pair for next step's readlane broadcast
        int own = (int)__builtin_bit_cast(unsigned short, (_Float16)h);
        int nb  = __builtin_amdgcn_update_dpp(0, own, 0xB1, 0xF, 0xF, true);
        int pk  = odd ? (nb | (own << 16)) : (own | (nb << 16));
        hpf = __builtin_bit_cast(float, pk);

        // prefetch x-gate 4 steps ahead
        int tp = t + 4; if (tp > SEQ - 1) tp = SEQ - 1;
        gq = gx[(size_t)tp * 64];
    };

    for (int t = 0; t < SEQ; t += 4) {
        step(gq0, t + 0);
        step(gq1, t + 1);
        step(gq2, t + 2);
        step(gq3, t + 3);
    }
}

// ---------------------------------------------------------------------------
// Kernel 3: attention, per-(head, t) — R8-EXACT (proven; R11 tweaks were
// neutral, reverted to minimize risk).
// grid: dim3(NH, SEQ), 256 threads.
// ---------------------------------------------------------------------------
#define SAS 68     // f32 stride of sA rows (16B-aligned)
#define SKVS 152   // f16 stride of qkv rows (304B, 16B-aligned): q@0,k@48,v@96
#define SSS 44     // f32 stride for score rows
__global__ void __launch_bounds__(256) k_attn(
    const float* __restrict__ seq,
    const float* __restrict__ Wq, const float* __restrict__ bq,
    const float* __restrict__ Wk, const float* __restrict__ bk,
    const float* __restrict__ Wv, const float* __restrict__ bv,
    float* __restrict__ o_buf)
{
    const int h = blockIdx.x, t = blockIdx.y, tid = threadIdx.x;
    __shared__ float sA[BATCH * SAS];          // 10.9 KB (f32)
    __shared__ _Float16 skqv[BATCH * SKVS];    // 12.2 KB
    __shared__ float ss[BATCH * SSS];          // 7.0 KB

    // ---- stage seq_t as f32 ----
    for (int i = tid; i < BATCH * D_LSTM; i += 256)
        sA[(i >> 6) * SAS + (i & 63)] = seq[(size_t)t * BATCH * D_LSTM + i];
    __syncthreads();

    // ---- projection: thread c (<144) owns one channel; f32 math ----
    if (tid < 144) {
        int m = tid / 48, d = tid - m * 48;
        const float* W = (m == 0) ? Wq : (m == 1) ? Wk : Wv;
        const float* B = (m == 0) ? bq : (m == 1) ? bk : bv;
        const float* wrow = W + (h * DH + d) * D_LSTM;
        float wreg[D_LSTM];
        {
            const v4f* wv = (const v4f*)wrow;   // coalesced f32 loads
            #pragma unroll
            for (int u = 0; u < 16; ++u) {
                v4f x = wv[u];
                wreg[4*u] = x.x; wreg[4*u+1] = x.y;
                wreg[4*u+2] = x.z; wreg[4*u+3] = x.w;
            }
        }
        const float bias = B[h * DH + d];

        for (int a = 0; a < BATCH; ++a) {
            const v4f* ap = (const v4f*)&sA[a * SAS];   // broadcast b128 reads
            float acc = bias;
            #pragma unroll
            for (int u = 0; u < 16; ++u) {
                v4f av = ap[u];
                acc += av.x * wreg[4*u]   + av.y * wreg[4*u+1]
                     + av.z * wreg[4*u+2] + av.w * wreg[4*u+3];
            }
            skqv[a * SKVS + tid] = (_Float16)acc;       // f16 store (proven)
        }
    }
    __syncthreads();

    // ---- scores = q k^T / 8 (f16 dots, R14-proven) ----
    for (int idx = tid; idx < BATCH * BATCH; idx += 256) {
        int i = idx / BATCH, jj = idx % BATCH;
        const v4f* qp = (const v4f*)&skqv[i * SKVS];        // q @ 0
        const v4f* kp = (const v4f*)&skqv[jj * SKVS + 48];  // k @ 48 (96B)
        float acc = 0.f;
        #pragma unroll
        for (int u = 0; u < 6; ++u) {
            v4f qv = qp[u], kv = kp[u];
            acc = __builtin_amdgcn_fdot2(__builtin_bit_cast(h2t, qv.x),
                    __builtin_bit_cast(h2t, kv.x), acc, false);
            acc = __builtin_amdgcn_fdot2(__builtin_bit_cast(h2t, qv.y),
                    __builtin_bit_cast(h2t, kv.y), acc, false);
            acc = __builtin_amdgcn_fdot2(__builtin_bit_cast(h2t, qv.z),
                    __builtin_bit_cast(h2t, kv.z), acc, false);
            acc = __builtin_amdgcn_fdot2(__builtin_bit_cast(h2t, qv.w),
                    __builtin_bit_cast(h2t, kv.w), acc, false);
        }
        ss[i * SSS + jj] = acc * 0.125f;
    }
    __syncthreads();

    // ---- row softmax (row in registers; R14-validated) ----
    if (tid < BATCH) {
        v4f* rp = (v4f*)&ss[tid * SSS];
        v4f r[10];
        #pragma unroll
        for (int u = 0; u < 10; ++u) r[u] = rp[u];
        float m = -1e30f;
        #pragma unroll
        for (int u = 0; u < 10; ++u)
            m = fmaxf(m, fmaxf(fmaxf(r[u].x, r[u].y), fmaxf(r[u].z, r[u].w)));
        float s = 0.f;
        #pragma unroll
        for (int u = 0; u < 10; ++u) {
            r[u].x = __expf(r[u].x - m); s += r[u].x;
            r[u].y = __expf(r[u].y - m); s += r[u].y;
            r[u].z = __expf(r[u].z - m); s += r[u].z;
            r[u].w = __expf(r[u].w - m); s += r[u].w;
        }
        float inv = __builtin_amdgcn_rcpf(s);
        #pragma unroll
        for (int u = 0; u < 10; ++u) {
            r[u].x *= inv; r[u].y *= inv; r[u].z *= inv; r[u].w *= inv;
            rp[u] = r[u];
        }
    }
    __syncthreads();

    // ---- AV: slot = (bi, 8 d's); 240 slots (R14-validated) ----
    if (tid < 240) {
        int bi = tid / 6, dg = tid % 6, d0 = dg * 8;
        const v4f* sp = (const v4f*)&ss[bi * SSS];
        v4f sr[10];
        #pragma unroll
        for (int u = 0; u < 10; ++u) sr[u] = sp[u];
        float acc[8];
        #pragma unroll
        for (int d = 0; d < 8; ++d) acc[d] = 0.f;
        for (int jj = 0; jj < 40; ++jj) {
            float a = ((const float*)&sr[jj >> 2])[jj & 3];
            v4f vv = *(const v4f*)&skqv[jj * SKVS + 96 + d0];  // v @ 96 (192B)
            #pragma unroll
            for (int w = 0; w < 4; ++w) {
                h2t pr = __builtin_bit_cast(h2t, ((const float*)&vv)[w]);
                acc[2 * w]     += a * (float)pr[0];
                acc[2 * w + 1] += a * (float)pr[1];
            }
        }
        float* ob = &o_buf[((size_t)t * BATCH + bi) * EMB + h * DH + d0];
        *(v4f*)&ob[0] = (v4f){acc[0], acc[1], acc[2], acc[3]};
        *(v4f*)&ob[4] = (v4f){acc[4], acc[5], acc[6], acc[7]};
    }
}

// ---------------------------------------------------------------------------
// Kernel 4: GLU + residual + LayerNorm — R8 base, p-loop load-clustered 4x:
// the wav/wgv row loads (16B/lane at 768B lane-stride -> gather) were 2
// latency-exposed loads per iteration x 48 iterations; now 8 loads
// clustered per group of 4 iterations (4x deeper MLP). Per-accumulator
// FP order identical (q ascending == p4 ascending). so reads unchanged.
// grid: 640 blocks, 256 threads.
// ---------------------------------------------------------------------------
__global__ void __launch_bounds__(256) k_glu_ln(
    const float* __restrict__ seq, const float* __restrict__ obuf,
    const float* __restrict__ Wa, const float* __restrict__ ba,
    const float* __restrict__ Wg, const float* __restrict__ bg,
    const float* __restrict__ gamma, const float* __restrict__ beta,
    float* __restrict__ out)
{
    const int t = blockIdx.x, tid = threadIdx.x;
    __shared__ __align__(16) float so[BATCH * 196];   // o_t padded (16B rows)
    __shared__ float sy[BATCH * 65];                  // y padded
    __shared__ float sseq[BATCH * D_LSTM];

    const float* ot = obuf + (size_t)t * BATCH * EMB;
    for (int i = tid; i < BATCH * EMB; i += 256)
        so[(i / EMB) * 196 + (i % EMB)] = ot[i];
    for (int i = tid; i < BATCH * D_LSTM; i += 256)
        sseq[i] = seq[(size_t)t * BATCH * D_LSTM + i];
    __syncthreads();

    const int j = tid >> 2, bgr = tid & 3;
    float acc_a[10], acc_g[10];
    #pragma unroll
    for (int bb = 0; bb < 10; ++bb) { acc_a[bb] = ba[j]; acc_g[bb] = bg[j]; }

    const v4f* wav = (const v4f*)(Wa + j * EMB);   // 768B rows, 16B-aligned
    const v4f* wgv = (const v4f*)(Wg + j * EMB);
    for (int pg = 0; pg < EMB / 16; ++pg) {        // 12 groups of 4 p4's
        v4f av[4], gv[4];
        #pragma unroll
        for (int q = 0; q < 4; ++q) av[q] = wav[4 * pg + q];
        #pragma unroll
        for (int q = 0; q < 4; ++q) gv[q] = wgv[4 * pg + q];
        #pragma unroll
        for (int q = 0; q < 4; ++q) {
            const int p4 = 4 * pg + q;
            #pragma unroll
            for (int bb = 0; bb < 10; ++bb) {
                v4f ov = *(const v4f*)&so[(bgr + 4 * bb) * 196 + 4 * p4];
                acc_a[bb] += ov.x * av[q].x;
                acc_a[bb] += ov.y * av[q].y;
                acc_a[bb] += ov.z * av[q].z;
                acc_a[bb] += ov.w * av[q].w;
                acc_g[bb] += ov.x * gv[q].x;
                acc_g[bb] += ov.y * gv[q].y;
                acc_g[bb] += ov.z * gv[q].z;
                acc_g[bb] += ov.w * gv[q].w;
            }
        }
    }
    #pragma unroll
    for (int bb = 0; bb < 10; ++bb) {
        int b = bgr + 4 * bb;
        float tv = acc_a[bb] * sigmoid_f(acc_g[bb]);
        sy[b * 65 + j] = sseq[b * D_LSTM + j] + tv;
    }
    __syncthreads();

    const int w = tid >> 6, lane = tid & 63;
    const float gm = gamma[lane], bt = beta[lane];
    for (int rr = 0; rr < 10; ++rr) {
        int b = w + 4 * rr;
        float y = sy[b * 65 + lane];
        float s1 = y, s2 = y * y;
        #pragma unroll
        for (int m = 1; m < 64; m <<= 1) {
            s1 += __shfl_xor(s1, m, 64);
            s2 += __shfl_xor(s2, m, 64);
        }
        float mu  = s1 * (1.f / 64.f);
        float var = s2 * (1.f / 64.f) - mu * mu;
        float inv = rsqrtf(var + 1e-5f);
        out[(size_t)t * BATCH * D_LSTM + b * D_LSTM + lane] =
            (y - mu) * inv * gm + bt;
    }
}

// ---------------------------------------------------------------------------
extern "C" void kernel_launch(void* const* d_in, const int* in_sizes, int n_in,
                              void* d_out, int out_size, void* d_ws, size_t ws_size,
                              hipStream_t stream)
{
    const float* hist = (const float*)d_in[0];
    // d_in[1] adj: unused (use_spatial=False)
    const float* W1   = (const float*)d_in[2];
    const float* b1   = (const float*)d_in[3];
    const float* W_ih = (const float*)d_in[4];
    const float* W_hh = (const float*)d_in[5];
    const float* b_ih = (const float*)d_in[6];
    const float* b_hh = (const float*)d_in[7];
    const float* Wq   = (const float*)d_in[8];
    const float* bq   = (const float*)d_in[9];
    const float* Wk   = (const float*)d_in[10];
    const float* bk   = (const float*)d_in[11];
    const float* Wv   = (const float*)d_in[12];
    const float* bv   = (const float*)d_in[13];
    const float* Wa   = (const float*)d_in[14];
    const float* ba   = (const float*)d_in[15];
    const float* Wg   = (const float*)d_in[16];
    const float* bg   = (const float*)d_in[17];
    const float* gamma = (const float*)d_in[18];
    const float* beta  = (const float*)d_in[19];
    float* out = (float*)d_out;

    float* ws = (float*)d_ws;
    float* gates_x = ws;                                   // 640*40*256 f
    float* seq     = ws + 6553600;                         // 640*40*64 f
    float* obuf    = ws + 6553600 + 1638400;               // 640*40*192 f

    hipLaunchKernelGGL(k_embed, dim3(SEQ), dim3(256), 0, stream,
                       hist, W1, b1, W_ih, b_ih, b_hh, gates_x);
    hipLaunchKernelGGL(k_lstm, dim3(BATCH), dim3(256), 0, stream,
                       gates_x, W_hh, seq);
    hipLaunchKernelGGL(k_attn, dim3(NH, SEQ), dim3(256), 0, stream,
                       seq, Wq, bq, Wk, bk, Wv, bv, obuf);
    hipLaunchKernelGGL(k_glu_ln, dim3(SEQ), dim3(256), 0, stream,
                       seq, obuf, Wa, ba, Wg, bg, gamma, beta, out);
}